// Round 4
// baseline (236.883 us; speedup 1.0000x reference)
//
#include <hip/hip_runtime.h>
#include <cstddef>
#include <cstdint>

#define SEQ    2048
#define NBATCH 2

typedef unsigned short u16;
typedef unsigned int   u32;
typedef __attribute__((ext_vector_type(8))) short bf16x8;  // 8 bf16 = 4 VGPRs
typedef __attribute__((ext_vector_type(4))) float f32x4;

#if __has_builtin(__builtin_amdgcn_exp2f)
#define EXP2F(x) __builtin_amdgcn_exp2f(x)
#else
#define EXP2F(x) exp2f(x)
#endif

__device__ __forceinline__ u32 fbits(float x) { union { float f; u32 u; } c; c.f = x; return c.u; }
__device__ __forceinline__ u16 f2bf(float x) { return (u16)((fbits(x) + 0x8000u) >> 16); }
// pack two floats -> (bf16(hi)<<16) | bf16(lo)
__device__ __forceinline__ u32 pack2bf(float lo, float hi) {
    return __builtin_amdgcn_perm(fbits(hi) + 0x8000u, fbits(lo) + 0x8000u, 0x07060302u);
}

// ---------------------------------------------------------------------------
// casts: fp32 -> bf16, 4 elems/thread, multiple tensors per launch (grid.y)
// ---------------------------------------------------------------------------
__global__ __launch_bounds__(256)
void cast3(const float* __restrict__ a, const float* __restrict__ b, const float* __restrict__ c,
           u16* __restrict__ oa, u16* __restrict__ ob, u16* __restrict__ oc, int n4)
{
    const float* s; u16* d;
    if (blockIdx.y == 0)      { s = a; d = oa; }
    else if (blockIdx.y == 1) { s = b; d = ob; }
    else                      { s = c; d = oc; }
    int i = blockIdx.x * 256 + threadIdx.x;
    if (i >= n4) return;
    float4 v = ((const float4*)s)[i];
    uint2 r; r.x = pack2bf(v.x, v.y); r.y = pack2bf(v.z, v.w);
    ((uint2*)d)[i] = r;
}

__global__ __launch_bounds__(256)
void cast4(const float* __restrict__ a, const float* __restrict__ b,
           const float* __restrict__ c, const float* __restrict__ e,
           u16* __restrict__ oa, u16* __restrict__ ob, u16* __restrict__ oc, u16* __restrict__ oe,
           int n4)
{
    const float* s; u16* d;
    if (blockIdx.y == 0)      { s = a; d = oa; }
    else if (blockIdx.y == 1) { s = b; d = ob; }
    else if (blockIdx.y == 2) { s = c; d = oc; }
    else                      { s = e; d = oe; }
    int i = blockIdx.x * 256 + threadIdx.x;
    if (i >= n4) return;
    float4 v = ((const float4*)s)[i];
    uint2 r; r.x = pack2bf(v.x, v.y); r.y = pack2bf(v.z, v.w);
    ((uint2*)d)[i] = r;
}

// ---------------------------------------------------------------------------
// GEMM body: Y = X @ W^T over K-range [kbeg,kend). M=4096, N=1024.
// 128x128 tile, BK=64, 256 thr (4 waves), wave = 64x64. Register-prefetch
// staging, LDS stride 72.
// layout 0: Y bf16 plain [m][1024]
// layout 2: Y bf16 transposed-through-LDS to [n,h,d,l]
// layout 3: Y fp32 plain (+bias if non-null)
// ---------------------------------------------------------------------------
__device__ __forceinline__
void gemm_body(const u16* __restrict__ X, const u16* __restrict__ W,
               void* __restrict__ Yv, const float* __restrict__ bias, const int layout,
               const int kbeg, const int kend)
{
    __shared__ u16 smem[2 * 128 * 72];
    u16* As = smem;
    u16* Bs = smem + 128 * 72;

    const int tid  = threadIdx.x;
    const int wave = tid >> 6;
    const int lane = tid & 63;
    const int lm   = lane & 15;
    const int quad = lane >> 4;
    const int m0 = blockIdx.x * 128;
    const int n0 = blockIdx.y * 128;
    const int wr = (wave & 1) * 64;
    const int wc = (wave >> 1) * 64;

    const int srow = tid >> 1;          // 0..127
    const int scol = (tid & 1) * 32;    // elem offset in k
    const u16* xg = X + (size_t)(m0 + srow) * 1024 + scol;
    const u16* wg = W + (size_t)(n0 + srow) * 1024 + scol;

    bf16x8 pa[4], pb[4];
    #pragma unroll
    for (int p = 0; p < 4; ++p) {
        pa[p] = *(const bf16x8*)(xg + kbeg + p * 8);
        pb[p] = *(const bf16x8*)(wg + kbeg + p * 8);
    }

    f32x4 acc[4][4] = {};

    for (int k0 = kbeg; k0 < kend; k0 += 64) {
        __syncthreads();   // previous iter's frag reads done
        #pragma unroll
        for (int p = 0; p < 4; ++p) {
            *(bf16x8*)&As[srow * 72 + scol + p * 8] = pa[p];
            *(bf16x8*)&Bs[srow * 72 + scol + p * 8] = pb[p];
        }
        __syncthreads();
        if (k0 + 64 < kend) {   // prefetch next K-step; in flight under MFMAs
            #pragma unroll
            for (int p = 0; p < 4; ++p) {
                pa[p] = *(const bf16x8*)(xg + k0 + 64 + p * 8);
                pb[p] = *(const bf16x8*)(wg + k0 + 64 + p * 8);
            }
        }
        #pragma unroll
        for (int kk = 0; kk < 64; kk += 32) {
            bf16x8 af[4], bf[4];
            #pragma unroll
            for (int t = 0; t < 4; ++t) {
                af[t] = *(const bf16x8*)&As[(wr + t * 16 + lm) * 72 + kk + quad * 8];
                bf[t] = *(const bf16x8*)&Bs[(wc + t * 16 + lm) * 72 + kk + quad * 8];
            }
            #pragma unroll
            for (int i = 0; i < 4; ++i)
                #pragma unroll
                for (int j = 0; j < 4; ++j)
                    acc[i][j] = __builtin_amdgcn_mfma_f32_16x16x32_bf16(af[i], bf[j], acc[i][j], 0, 0, 0);
        }
    }

    if (layout == 3) {
        float* Y = (float*)Yv;
        #pragma unroll
        for (int i = 0; i < 4; ++i)
            #pragma unroll
            for (int j = 0; j < 4; ++j) {
                const int C = n0 + wc + j * 16 + lm;
                const float bv = bias ? bias[C] : 0.0f;
                #pragma unroll
                for (int r = 0; r < 4; ++r) {
                    const int R = m0 + wr + i * 16 + quad * 4 + r;
                    Y[(size_t)R * 1024 + C] = acc[i][j][r] + bv;
                }
            }
    } else if (layout == 0) {
        u16* Y = (u16*)Yv;
        #pragma unroll
        for (int i = 0; i < 4; ++i)
            #pragma unroll
            for (int j = 0; j < 4; ++j) {
                const int C = n0 + wc + j * 16 + lm;
                #pragma unroll
                for (int r = 0; r < 4; ++r) {
                    const int R = m0 + wr + i * 16 + quad * 4 + r;
                    Y[(size_t)R * 1024 + C] = f2bf(acc[i][j][r]);
                }
            }
    } else {
        // layout 2: transpose 128x128 C-tile through LDS, store [n,h,d,l]
        __syncthreads();            // all MFMA frag reads of As/Bs done
        u16* T = smem;              // [d_local][l_local], stride 132
        #pragma unroll
        for (int i = 0; i < 4; ++i)
            #pragma unroll
            for (int j = 0; j < 4; ++j) {
                const int col = wc + j * 16 + lm;           // d_local
                const int row = wr + i * 16 + quad * 4;     // l_local
                uint2 v;
                v.x = pack2bf(acc[i][j][0], acc[i][j][1]);
                v.y = pack2bf(acc[i][j][2], acc[i][j][3]);
                *(uint2*)&T[col * 132 + row] = v;
            }
        __syncthreads();
        const int dp = tid >> 1, half = (tid & 1) * 64;
        const int nn = m0 >> 11, l0 = m0 & 2047;
        const int C = n0 + dp, h = C >> 6, d = C & 63;
        u16* Y = (u16*)Yv;
        const size_t base = (((size_t)nn * 16 + h) * 64 + d) * SEQ + l0 + half;
        #pragma unroll
        for (int p = 0; p < 8; ++p) {
            bf16x8 v = *(const bf16x8*)&T[dp * 132 + half + p * 8];
            *(bf16x8*)(Y + base + p * 8) = v;
        }
    }
}

__global__ __launch_bounds__(256, 2)
void gemm_qkv(const u16* __restrict__ xq, const u16* __restrict__ xk, const u16* __restrict__ xv,
              const u16* __restrict__ wq, const u16* __restrict__ wk, const u16* __restrict__ wv,
              u16* __restrict__ qb, u16* __restrict__ kb, u16* __restrict__ vt)
{
    if (blockIdx.z == 0)      gemm_body(xq, wq, qb, nullptr, 0, 0, 1024);
    else if (blockIdx.z == 1) gemm_body(xk, wk, kb, nullptr, 0, 0, 1024);
    else                      gemm_body(xv, wv, vt, nullptr, 2, 0, 1024);
}

// split-K output GEMM: z in {0,1} does K-half into its own fp32 partial
__global__ __launch_bounds__(256, 2)
void gemm_out_split(const u16* __restrict__ X, const u16* __restrict__ W,
                    float* __restrict__ p0, float* __restrict__ p1)
{
    if (blockIdx.z == 0) gemm_body(X, W, p0, nullptr, 3, 0, 512);
    else                 gemm_body(X, W, p1, nullptr, 3, 512, 1024);
}

__global__ __launch_bounds__(256)
void reduce_bias(const float* __restrict__ p0, const float* __restrict__ p1,
                 const float* __restrict__ bias, float* __restrict__ out)
{
    const int i = blockIdx.x * 256 + threadIdx.x;   // float4 index, 1M total
    float4 a = ((const float4*)p0)[i];
    float4 b = ((const float4*)p1)[i];
    float4 c = ((const float4*)bias)[i & 255];
    float4 o;
    o.x = a.x + b.x + c.x; o.y = a.y + b.y + c.y;
    o.z = a.z + b.z + c.z; o.w = a.w + b.w + c.w;
    ((float4*)out)[i] = o;
}

// ---------------------------------------------------------------------------
// Flash attention, bf16 MFMA, max-free softmax, key-chunk = 128 with
// two-half P/PV (Ps is wave-private, reused per 64-key half -> no barrier).
// Block = 256 thr (4 waves) = 128 q-rows of one (n,h); wave owns 32 q-rows.
// Qb,Kb: [n,l,1024] bf16.  VT: [n,h,d,l] bf16.  O: [n,l,1024] bf16.
// LDS: Ks 18.4K + Vts 17.4K + Ps 18.4K = 53K -> 2 blocks/CU.
// ---------------------------------------------------------------------------
__global__ __launch_bounds__(256, 2)
void flash_attn_bf16(const u16* __restrict__ Qb, const u16* __restrict__ Kb,
                     const u16* __restrict__ VT, const int* __restrict__ mask,
                     u16* __restrict__ O)
{
    __shared__ u16 Ks[128 * 72];      // [key l][d]
    __shared__ u16 Vts[64 * 136];     // [d][key l]
    __shared__ u16 Ps[4][32 * 72];    // per-wave P [q][key-half]

    const int tid  = threadIdx.x;
    const int wave = tid >> 6;
    const int lane = tid & 63;
    const int lm   = lane & 15;
    const int quad = lane >> 4;
    const int h = blockIdx.y, n = blockIdx.z;
    const int wq = blockIdx.x * 128 + wave * 32;

    const u16* Qh = Qb + ((size_t)n * SEQ) * 1024 + h * 64;
    const u16* Kh = Kb + ((size_t)n * SEQ) * 1024 + h * 64;
    const u16* Vh = VT + (((size_t)n * 16 + h) * 64) * SEQ;
    const int* mk = mask + (size_t)n * SEQ;
    u16* Pw = &Ps[wave][0];

    // Q fragments resident: A-layout m=lm, k=quad*8+j
    bf16x8 qf[2][2];
    #pragma unroll
    for (int t = 0; t < 2; ++t)
        #pragma unroll
        for (int s = 0; s < 2; ++s)
            qf[t][s] = *(const bf16x8*)(Qh + (size_t)(wq + t * 16 + lm) * 1024 + s * 32 + quad * 8);

    f32x4 o_acc[2][4] = {};
    float l_i[2][4] = {};

    // staging coords: K 128 rows x 64 d (2 thr/row); V 64 d x 128 keys (4 thr/row)
    const int kr = tid >> 1, kc = (tid & 1) * 32;
    const int vr = tid >> 2, vc = (tid & 3) * 32;

    bf16x8 ka[4], va[4];
    #pragma unroll
    for (int p = 0; p < 4; ++p) {
        ka[p] = *(const bf16x8*)(Kh + (size_t)kr * 1024 + kc + p * 8);
        va[p] = *(const bf16x8*)(Vh + (size_t)vr * SEQ + vc + p * 8);
    }

    const float cs = 0.125f * 1.44269504f;   // score scale folded with log2(e)

    for (int c0 = 0; c0 < SEQ; c0 += 128) {
        __syncthreads();   // prior chunk's Ks/Vts reads complete
        #pragma unroll
        for (int p = 0; p < 4; ++p) {
            *(bf16x8*)&Ks[kr * 72 + kc + p * 8]   = ka[p];
            *(bf16x8*)&Vts[vr * 136 + vc + p * 8] = va[p];
        }
        __syncthreads();

        if (c0 + 128 < SEQ) {   // prefetch next chunk; in flight under compute
            #pragma unroll
            for (int p = 0; p < 4; ++p) {
                ka[p] = *(const bf16x8*)(Kh + (size_t)(c0 + 128 + kr) * 1024 + kc + p * 8);
                va[p] = *(const bf16x8*)(Vh + (size_t)vr * SEQ + c0 + 128 + vc + p * 8);
            }
        }

        // ---- S = Q K^T over 128 keys (8 n-tiles, 32 MFMAs)
        f32x4 s[2][8] = {};
        #pragma unroll
        for (int nt = 0; nt < 8; ++nt) {
            bf16x8 kf0 = *(const bf16x8*)&Ks[(nt * 16 + lm) * 72 + quad * 8];
            bf16x8 kf1 = *(const bf16x8*)&Ks[(nt * 16 + lm) * 72 + 32 + quad * 8];
            #pragma unroll
            for (int t = 0; t < 2; ++t) {
                s[t][nt] = __builtin_amdgcn_mfma_f32_16x16x32_bf16(qf[t][0], kf0, s[t][nt], 0, 0, 0);
                s[t][nt] = __builtin_amdgcn_mfma_f32_16x16x32_bf16(qf[t][1], kf1, s[t][nt], 0, 0, 0);
            }
        }

        // ---- exp2(scale*s), mask, row-sum accumulation (max-free)
        int msk[8];
        #pragma unroll
        for (int nt = 0; nt < 8; ++nt) msk[nt] = mk[c0 + nt * 16 + lm];
        #pragma unroll
        for (int t = 0; t < 2; ++t)
            #pragma unroll
            for (int nt = 0; nt < 8; ++nt)
                #pragma unroll
                for (int r = 0; r < 4; ++r) {
                    float e = EXP2F(s[t][nt][r] * cs);
                    e = msk[nt] ? e : 0.0f;
                    s[t][nt][r] = e;
                    l_i[t][r] += e;
                }

        // ---- two key-halves: P -> wave-private LDS, then PV (no barriers)
        #pragma unroll
        for (int half = 0; half < 2; ++half) {
            #pragma unroll
            for (int t = 0; t < 2; ++t)
                #pragma unroll
                for (int ntl = 0; ntl < 4; ++ntl)
                    #pragma unroll
                    for (int r = 0; r < 4; ++r)
                        Pw[(t * 16 + quad * 4 + r) * 72 + ntl * 16 + lm] =
                            f2bf(s[t][half * 4 + ntl][r]);

            #pragma unroll
            for (int ksl = 0; ksl < 2; ++ksl) {
                bf16x8 pf[2];
                #pragma unroll
                for (int t = 0; t < 2; ++t)
                    pf[t] = *(const bf16x8*)&Pw[(t * 16 + lm) * 72 + ksl * 32 + quad * 8];
                #pragma unroll
                for (int dt = 0; dt < 4; ++dt) {
                    bf16x8 vf = *(const bf16x8*)&Vts[(dt * 16 + lm) * 136 + half * 64 + ksl * 32 + quad * 8];
                    #pragma unroll
                    for (int t = 0; t < 2; ++t)
                        o_acc[t][dt] = __builtin_amdgcn_mfma_f32_16x16x32_bf16(pf[t], vf, o_acc[t][dt], 0, 0, 0);
                }
            }
        }
    }

    // ---- epilogue: one l reduction, normalize, store
    #pragma unroll
    for (int t = 0; t < 2; ++t)
        #pragma unroll
        for (int r = 0; r < 4; ++r) {
            float v = l_i[t][r];
            #pragma unroll
            for (int off = 1; off < 16; off <<= 1) v += __shfl_xor(v, off);
            l_i[t][r] = 1.0f / v;
        }
    #pragma unroll
    for (int t = 0; t < 2; ++t)
        #pragma unroll
        for (int dt = 0; dt < 4; ++dt)
            #pragma unroll
            for (int r = 0; r < 4; ++r) {
                const int ql = wq + t * 16 + quad * 4 + r;
                const int col = h * 64 + dt * 16 + lm;
                O[((size_t)n * SEQ + ql) * 1024 + col] = f2bf(o_acc[t][dt][r] * l_i[t][r]);
            }
}

// ---------------------------------------------------------------------------
extern "C" void kernel_launch(void* const* d_in, const int* in_sizes, int n_in,
                              void* d_out, int out_size, void* d_ws, size_t ws_size,
                              hipStream_t stream)
{
    const float* values = (const float*)d_in[0];
    const float* keys   = (const float*)d_in[1];
    const float* query  = (const float*)d_in[2];
    const int*   mask   = (const int*)d_in[3];
    const float* W_q    = (const float*)d_in[4];
    const float* W_k    = (const float*)d_in[5];
    const float* W_v    = (const float*)d_in[6];
    const float* W_o    = (const float*)d_in[7];
    const float* b_o    = (const float*)d_in[8];

    const size_t NTOK = (size_t)NBATCH * SEQ * 1024;  // 4194304
    const size_t WSZ  = 1024 * 1024;
    u16* p = (u16*)d_ws;
    u16* qb    = p; p += NTOK;   // q  [n,l,e] bf16          (dead after flash)
    u16* kb    = p; p += NTOK;   // k  [n,l,e] bf16          (dead after flash)
    u16* vt    = p; p += NTOK;   // v^T[n,h,d,l] bf16        (dead after flash)
    u16* xq    = p; p += NTOK;   // bf16 input casts         (dead after qkv)
    u16* xk    = p; p += NTOK;
    u16* xv    = p; p += NTOK;
    u16* attnb = p; p += NTOK;   // attn out [n,l,e] bf16    (live into gemm_out)
    u16* wqb   = p; p += WSZ;    // bf16 weight casts
    u16* wkb   = p; p += WSZ;
    u16* wvb   = p; p += WSZ;
    u16* wob   = p; p += WSZ;
    // split-K fp32 partials alias dead regions (qb+kb = 16MB, vt+xq = 16MB)
    float* part0 = (float*)qb;
    float* part1 = (float*)vt;

    cast3<<<dim3(4096, 3), 256, 0, stream>>>(query, keys, values, xq, xk, xv, (int)(NTOK / 4));
    cast4<<<dim3(1024, 4), 256, 0, stream>>>(W_q, W_k, W_v, W_o, wqb, wkb, wvb, wob, (int)(WSZ / 4));

    gemm_qkv<<<dim3(32, 8, 3), 256, 0, stream>>>(xq, xk, xv, wqb, wkb, wvb, qb, kb, vt);

    flash_attn_bf16<<<dim3(16, 16, 2), 256, 0, stream>>>(qb, kb, vt, mask, attnb);

    gemm_out_split<<<dim3(32, 8, 2), 256, 0, stream>>>(attnb, wob, part0, part1);
    reduce_bias<<<4096, 256, 0, stream>>>(part0, part1, b_o, (float*)d_out);
}